// Round 1
// baseline (1401.336 us; speedup 1.0000x reference)
//
#include <hip/hip_runtime.h>

#define NN 20000
#define NE 640000

typedef __attribute__((ext_vector_type(4))) float f4;
typedef __attribute__((ext_vector_type(8))) unsigned short us8;
typedef __attribute__((ext_vector_type(8))) __bf16 bf8;
typedef __attribute__((ext_vector_type(4))) int i4;

__device__ __forceinline__ unsigned short f2bf(float f) {
    union { float f; unsigned int u; } v; v.f = f;
    unsigned int u = v.u;
    return (unsigned short)((u + 0x7FFFu + ((u >> 16) & 1u)) >> 16);
}
__device__ __forceinline__ float bf2f(unsigned short b) {
    union { unsigned int u; float f; } v; v.u = ((unsigned int)b) << 16; return v.f;
}
__device__ __forceinline__ f4 mfma16(us8 a, us8 b, f4 c) {
    return __builtin_amdgcn_mfma_f32_16x16x32_bf16(
        __builtin_bit_cast(bf8, a), __builtin_bit_cast(bf8, b), c, 0, 0, 0);
}

// ---------------- weight prep: transpose + bf16 ----------------
__global__ void __launch_bounds__(256) prep_weights(
    const float* __restrict__ eW1, const float* __restrict__ eW2,
    const float* __restrict__ nW1, const float* __restrict__ nW2,
    const float* __restrict__ cW1,
    unsigned short* __restrict__ eW1T, unsigned short* __restrict__ eW2T,
    unsigned short* __restrict__ nW1T, unsigned short* __restrict__ nW2T,
    unsigned short* __restrict__ cW1T, float* __restrict__ ew1last)
{
    int i = blockIdx.x * 256 + threadIdx.x;
    if (i < 32768) { int f = i >> 8, k = i & 255; eW1T[i] = f2bf(eW1[k * 128 + f]); return; }
    i -= 32768;
    if (i < 16384) { int f = i >> 7, k = i & 127; eW2T[i] = f2bf(eW2[k * 128 + f]); return; }
    i -= 16384;
    if (i < 32768) { int f = i >> 8, k = i & 255; nW1T[i] = f2bf(nW1[k * 128 + f]); return; }
    i -= 32768;
    if (i < 16384) { int f = i >> 7, k = i & 127; nW2T[i] = f2bf(nW2[k * 128 + f]); return; }
    i -= 16384;
    if (i < 16384) { int f = i >> 7, k = i & 127; cW1T[i] = f2bf(cW1[k * 128 + f]); return; }
    i -= 16384;
    if (i < 128) { ew1last[i] = eW1[256 * 128 + i]; }
}

// ---------------- embedding + state init ----------------
__global__ void __launch_bounds__(128) embed_init(
    const float* __restrict__ h_in, const float* __restrict__ x_in,
    const float* __restrict__ embW, const float* __restrict__ embB,
    float* __restrict__ h_cur, unsigned short* __restrict__ h_bf,
    float* __restrict__ x_cur, float* __restrict__ m, float* __restrict__ xu)
{
    int n = blockIdx.x, f = threadIdx.x;
    float acc = embB[f];
#pragma unroll
    for (int p = 0; p < 16; p++) acc += h_in[n * 16 + p] * embW[p * 128 + f];
    h_cur[n * 128 + f] = acc;
    h_bf[n * 128 + f] = f2bf(acc);
    m[n * 128 + f] = 0.f;
    if (f < 3) { x_cur[n * 3 + f] = x_in[n * 3 + f]; xu[n * 3 + f] = 0.f; }
}

// ---------------- fused edge kernel ----------------
// 32 edges/block, 256 threads (4 waves: wm in {0,1} edge-half, wn in {0,1} feat-half)
__global__ void __launch_bounds__(256) edge_kernel(
    const int* __restrict__ eidx,
    const unsigned short* __restrict__ h_bf,
    const float* __restrict__ x_cur,
    const unsigned short* __restrict__ eW1T, const unsigned short* __restrict__ eW2T,
    const unsigned short* __restrict__ cW1T, const float* __restrict__ ew1last,
    const float* __restrict__ eb1, const float* __restrict__ eb2,
    const float* __restrict__ cb1, const float* __restrict__ cb2,
    const float* __restrict__ cW2,
    float* __restrict__ m, float* __restrict__ xu)
{
    __shared__ unsigned short At[32 * 256];   // edge_feat tile, 16KB, swizzled
    __shared__ unsigned short zb[32 * 128];   // z1 / z3, 8KB, swizzled
    __shared__ unsigned short ebf[32 * 128];  // e_ij, 8KB, swizzled
    __shared__ int rowS[32], colS[32];
    __shared__ float rpS[32][3];
    __shared__ float rdS[32];

    const int t = threadIdx.x;
    const int e0 = blockIdx.x * 32;

    if (t < 32) {
        int r = eidx[e0 + t], c = eidx[NE + e0 + t];
        rowS[t] = r; colS[t] = c;
        float dx = x_cur[r * 3 + 0] - x_cur[c * 3 + 0];
        float dy = x_cur[r * 3 + 1] - x_cur[c * 3 + 1];
        float dz = x_cur[r * 3 + 2] - x_cur[c * 3 + 2];
        rpS[t][0] = dx; rpS[t][1] = dy; rpS[t][2] = dz;
        rdS[t] = dx * dx + dy * dy + dz * dz;
    }
    __syncthreads();

    // gather [h_row | h_col] -> At (bf16), 16B chunks
#pragma unroll
    for (int i = 0; i < 4; i++) {
        int c = i * 256 + t;              // 0..1023
        int e = c >> 5, half = (c >> 4) & 1, q = c & 15;
        int node = half ? colS[e] : rowS[e];
        i4 v = *reinterpret_cast<const i4*>(h_bf + node * 128 + q * 8);
        int dst = (e * 512 + half * 256 + q * 16) ^ ((e & 7) << 4);
        *reinterpret_cast<i4*>(reinterpret_cast<char*>(At) + dst) = v;
    }
    __syncthreads();

    const int lane = t & 63, w = t >> 6;
    const int wm = w & 1, wn = w >> 1;
    const int lr = lane & 15, lg = lane >> 4;
    const int eA = wm * 16 + lr;      // A-frag row (edge)
    const int eC0 = wm * 16 + lg * 4; // C-frag row base (edge)

    // ---- GEMM1: z1 = relu(edge_feat @ eW1 + eb1 + rd*w_last) ----
    us8 af[8];
#pragma unroll
    for (int ks = 0; ks < 8; ks++) {
        int ad = (eA * 512 + ks * 64 + lg * 16) ^ ((eA & 7) << 4);
        af[ks] = *reinterpret_cast<const us8*>(reinterpret_cast<char*>(At) + ad);
    }
    float rd4[4];
#pragma unroll
    for (int r = 0; r < 4; r++) rd4[r] = rdS[eC0 + r];

#pragma unroll
    for (int nt = 0; nt < 4; nt++) {
        int feat = wn * 64 + nt * 16 + lr;
        const unsigned short* bp = eW1T + feat * 256 + lg * 8;
        f4 a = {0.f, 0.f, 0.f, 0.f};
#pragma unroll
        for (int ks = 0; ks < 8; ks++)
            a = mfma16(af[ks], *reinterpret_cast<const us8*>(bp + ks * 32), a);
        float bias = eb1[feat], wl = ew1last[feat];
#pragma unroll
        for (int r = 0; r < 4; r++) {
            float z = a[r] + bias + rd4[r] * wl;
            z = z > 0.f ? z : 0.f;
            int e = eC0 + r;
            int ad = (e * 256 + feat * 2) ^ ((e & 7) << 4);
            *reinterpret_cast<unsigned short*>(reinterpret_cast<char*>(zb) + ad) = f2bf(z);
        }
    }
    __syncthreads();

    // ---- GEMM2: e_ij = z1 @ eW2 + eb2 ; atomics into m ; stash bf16 ----
    us8 af2[4];
#pragma unroll
    for (int ks = 0; ks < 4; ks++) {
        int ad = (eA * 256 + ks * 64 + lg * 16) ^ ((eA & 7) << 4);
        af2[ks] = *reinterpret_cast<const us8*>(reinterpret_cast<char*>(zb) + ad);
    }
    int row4[4];
#pragma unroll
    for (int r = 0; r < 4; r++) row4[r] = rowS[eC0 + r];

#pragma unroll
    for (int nt = 0; nt < 4; nt++) {
        int feat = wn * 64 + nt * 16 + lr;
        const unsigned short* bp = eW2T + feat * 128 + lg * 8;
        f4 a = {0.f, 0.f, 0.f, 0.f};
#pragma unroll
        for (int ks = 0; ks < 4; ks++)
            a = mfma16(af2[ks], *reinterpret_cast<const us8*>(bp + ks * 32), a);
        float bias = eb2[feat];
#pragma unroll
        for (int r = 0; r < 4; r++) {
            float v = a[r] + bias;
            atomicAdd(&m[row4[r] * 128 + feat], v);
            int e = eC0 + r;
            int ad = (e * 256 + feat * 2) ^ ((e & 7) << 4);
            *reinterpret_cast<unsigned short*>(reinterpret_cast<char*>(ebf) + ad) = f2bf(v);
        }
    }
    __syncthreads();

    // ---- GEMM3: z3 = relu(e_ij @ cW1 + cb1) ----
    us8 af3[4];
#pragma unroll
    for (int ks = 0; ks < 4; ks++) {
        int ad = (eA * 256 + ks * 64 + lg * 16) ^ ((eA & 7) << 4);
        af3[ks] = *reinterpret_cast<const us8*>(reinterpret_cast<char*>(ebf) + ad);
    }
#pragma unroll
    for (int nt = 0; nt < 4; nt++) {
        int feat = wn * 64 + nt * 16 + lr;
        const unsigned short* bp = cW1T + feat * 128 + lg * 8;
        f4 a = {0.f, 0.f, 0.f, 0.f};
#pragma unroll
        for (int ks = 0; ks < 4; ks++)
            a = mfma16(af3[ks], *reinterpret_cast<const us8*>(bp + ks * 32), a);
        float bias = cb1[feat];
#pragma unroll
        for (int r = 0; r < 4; r++) {
            float z = a[r] + bias;
            z = z > 0.f ? z : 0.f;
            int e = eC0 + r;
            int ad = (e * 256 + feat * 2) ^ ((e & 7) << 4);
            *reinterpret_cast<unsigned short*>(reinterpret_cast<char*>(zb) + ad) = f2bf(z);
        }
    }
    __syncthreads();

    // ---- alpha = z3 @ cW2 + cb2 ; x-update atomics ----
    {
        int e = t >> 3, s = t & 7;
        float sum = 0.f;
#pragma unroll
        for (int hf = 0; hf < 2; hf++) {
            int ad = (e * 256 + s * 32 + hf * 16) ^ ((e & 7) << 4);
            us8 v = *reinterpret_cast<const us8*>(reinterpret_cast<char*>(zb) + ad);
#pragma unroll
            for (int j = 0; j < 8; j++)
                sum += bf2f((unsigned short)v[j]) * cW2[s * 16 + hf * 8 + j];
        }
        sum += __shfl_xor(sum, 1, 64);
        sum += __shfl_xor(sum, 2, 64);
        sum += __shfl_xor(sum, 4, 64);
        if (s == 0) {
            float alpha = sum + cb2[0];
            int r = rowS[e];
            atomicAdd(&xu[r * 3 + 0], alpha * rpS[e][0]);
            atomicAdd(&xu[r * 3 + 1], alpha * rpS[e][1]);
            atomicAdd(&xu[r * 3 + 2], alpha * rpS[e][2]);
        }
    }
}

// ---------------- node update kernel ----------------
// 32 nodes/block, 256 threads
__global__ void __launch_bounds__(256) node_kernel(
    const unsigned short* __restrict__ nW1T, const unsigned short* __restrict__ nW2T,
    const float* __restrict__ nb1, const float* __restrict__ nb2,
    float* __restrict__ h_cur, unsigned short* __restrict__ h_bf,
    float* __restrict__ m, float* __restrict__ x_cur, float* __restrict__ xu)
{
    __shared__ unsigned short At[32 * 256];
    __shared__ unsigned short zb[32 * 128];
    const int t = threadIdx.x;
    const int n0 = blockIdx.x * 32;

    // build A = [h | m] in bf16
#pragma unroll
    for (int i = 0; i < 4; i++) {
        int c = i * 256 + t;
        int nd = c >> 5, q = c & 31;
        const float* src = (q >= 16 ? m : h_cur) + (n0 + nd) * 128 + (q & 15) * 8;
        f4 x0 = *reinterpret_cast<const f4*>(src);
        f4 x1 = *reinterpret_cast<const f4*>(src + 4);
        us8 o;
        o[0] = f2bf(x0[0]); o[1] = f2bf(x0[1]); o[2] = f2bf(x0[2]); o[3] = f2bf(x0[3]);
        o[4] = f2bf(x1[0]); o[5] = f2bf(x1[1]); o[6] = f2bf(x1[2]); o[7] = f2bf(x1[3]);
        int dst = (nd * 512 + q * 16) ^ ((nd & 7) << 4);
        *reinterpret_cast<us8*>(reinterpret_cast<char*>(At) + dst) = o;
    }
    __syncthreads();

    const int lane = t & 63, w = t >> 6;
    const int wm = w & 1, wn = w >> 1;
    const int lr = lane & 15, lg = lane >> 4;
    const int nA = wm * 16 + lr;
    const int nC0 = wm * 16 + lg * 4;

    // GEMM1: z = relu([h|m] @ nW1 + nb1)
    us8 af[8];
#pragma unroll
    for (int ks = 0; ks < 8; ks++) {
        int ad = (nA * 512 + ks * 64 + lg * 16) ^ ((nA & 7) << 4);
        af[ks] = *reinterpret_cast<const us8*>(reinterpret_cast<char*>(At) + ad);
    }
#pragma unroll
    for (int nt = 0; nt < 4; nt++) {
        int feat = wn * 64 + nt * 16 + lr;
        const unsigned short* bp = nW1T + feat * 256 + lg * 8;
        f4 a = {0.f, 0.f, 0.f, 0.f};
#pragma unroll
        for (int ks = 0; ks < 8; ks++)
            a = mfma16(af[ks], *reinterpret_cast<const us8*>(bp + ks * 32), a);
        float bias = nb1[feat];
#pragma unroll
        for (int r = 0; r < 4; r++) {
            float z = a[r] + bias;
            z = z > 0.f ? z : 0.f;
            int nd = nC0 + r;
            int ad = (nd * 256 + feat * 2) ^ ((nd & 7) << 4);
            *reinterpret_cast<unsigned short*>(reinterpret_cast<char*>(zb) + ad) = f2bf(z);
        }
    }
    __syncthreads();

    // GEMM2: h = h + (z @ nW2 + nb2)
    us8 af2[4];
#pragma unroll
    for (int ks = 0; ks < 4; ks++) {
        int ad = (nA * 256 + ks * 64 + lg * 16) ^ ((nA & 7) << 4);
        af2[ks] = *reinterpret_cast<const us8*>(reinterpret_cast<char*>(zb) + ad);
    }
#pragma unroll
    for (int nt = 0; nt < 4; nt++) {
        int feat = wn * 64 + nt * 16 + lr;
        const unsigned short* bp = nW2T + feat * 128 + lg * 8;
        f4 a = {0.f, 0.f, 0.f, 0.f};
#pragma unroll
        for (int ks = 0; ks < 4; ks++)
            a = mfma16(af2[ks], *reinterpret_cast<const us8*>(bp + ks * 32), a);
        float bias = nb2[feat];
#pragma unroll
        for (int r = 0; r < 4; r++) {
            int nd = nC0 + r;
            int gi = (n0 + nd) * 128 + feat;
            float v = h_cur[gi] + a[r] + bias;
            h_cur[gi] = v;
            h_bf[gi] = f2bf(v);
        }
    }

    // x += xu ; zero xu ; zero m (all phase-1 m reads are behind barriers)
    if (t < 96) {
        int nd = t / 3, d = t - nd * 3;
        int gi = (n0 + nd) * 3 + d;
        x_cur[gi] += xu[gi];
        xu[gi] = 0.f;
    }
#pragma unroll
    for (int i = 0; i < 16; i++) m[n0 * 128 + i * 256 + t] = 0.f;
}

__global__ void __launch_bounds__(256) writeout(
    const float* __restrict__ h_cur, const float* __restrict__ x_cur,
    float* __restrict__ out)
{
    int i = blockIdx.x * 256 + threadIdx.x;
    if (i < NN * 128) out[i] = h_cur[i];
    else {
        int j = i - NN * 128;
        if (j < NN * 3) out[i] = x_cur[j];
    }
}

extern "C" void kernel_launch(void* const* d_in, const int* in_sizes, int n_in,
                              void* d_out, int out_size, void* d_ws, size_t ws_size,
                              hipStream_t stream)
{
    (void)in_sizes; (void)n_in; (void)out_size; (void)ws_size;
    const float* h_in = (const float*)d_in[0];
    const float* x_in = (const float*)d_in[1];
    const int* eidx   = (const int*)d_in[2];
    const float* embW = (const float*)d_in[3];
    const float* embB = (const float*)d_in[4];
    const float* eW1  = (const float*)d_in[5];
    const float* eb1  = (const float*)d_in[6];
    const float* eW2  = (const float*)d_in[7];
    const float* eb2  = (const float*)d_in[8];
    const float* nW1  = (const float*)d_in[9];
    const float* nb1  = (const float*)d_in[10];
    const float* nW2  = (const float*)d_in[11];
    const float* nb2  = (const float*)d_in[12];
    const float* cW1  = (const float*)d_in[13];
    const float* cb1  = (const float*)d_in[14];
    const float* cW2  = (const float*)d_in[15];
    const float* cb2  = (const float*)d_in[16];

    char* ws = (char*)d_ws;
    size_t off = 0;
    auto alloc = [&](size_t bytes) -> char* {
        char* p = ws + off;
        off += (bytes + 255) & ~size_t(255);
        return p;
    };
    float* h_cur = (float*)alloc((size_t)NN * 128 * 4);
    float* m     = (float*)alloc((size_t)NN * 128 * 4);
    unsigned short* h_bf = (unsigned short*)alloc((size_t)NN * 128 * 2);
    float* x_cur = (float*)alloc((size_t)NN * 3 * 4);
    float* xu    = (float*)alloc((size_t)NN * 3 * 4);
    unsigned short* eW1T = (unsigned short*)alloc(128 * 256 * 2);
    unsigned short* eW2T = (unsigned short*)alloc(128 * 128 * 2);
    unsigned short* nW1T = (unsigned short*)alloc(128 * 256 * 2);
    unsigned short* nW2T = (unsigned short*)alloc(128 * 128 * 2);
    unsigned short* cW1T = (unsigned short*)alloc(128 * 128 * 2);
    float* ew1last = (float*)alloc(128 * 4);

    prep_weights<<<449, 256, 0, stream>>>(eW1, eW2, nW1, nW2, cW1,
                                          eW1T, eW2T, nW1T, nW2T, cW1T, ew1last);
    embed_init<<<NN, 128, 0, stream>>>(h_in, x_in, embW, embB,
                                       h_cur, h_bf, x_cur, m, xu);
    for (int l = 0; l < 2; l++) {
        edge_kernel<<<NE / 32, 256, 0, stream>>>(eidx, h_bf, x_cur,
                                                 eW1T, eW2T, cW1T, ew1last,
                                                 eb1, eb2, cb1, cb2, cW2, m, xu);
        node_kernel<<<NN / 32, 256, 0, stream>>>(nW1T, nW2T, nb1, nb2,
                                                 h_cur, h_bf, m, x_cur, xu);
    }
    writeout<<<(NN * 128 + NN * 3 + 255) / 256, 256, 0, stream>>>(h_cur, x_cur, (float*)d_out);
}